// Round 13
// baseline (134.165 us; speedup 1.0000x reference)
//
#include <hip/hip_runtime.h>
#include <hip/hip_bf16.h>
#include <math.h>

#define BB 64
#define TT 512
#define IW 256
#define HH 512
#define G3H 1536
#define PEN1 (1<<20)

__device__ __forceinline__ double dshfl_xor(double v, int m){
  int2 a = *(int2*)&v;
  a.x = __shfl_xor(a.x, m, 64);
  a.y = __shfl_xor(a.y, m, 64);
  return *(double*)&a;
}

__global__ void sentinel_k(float* out, float v){ out[0] = v; }

// ---------- layer-0 gates (stages x-slice in LDS, transposed) + colsum tail blocks ----------
__global__ __launch_bounds__(256) void gates0x(const float* __restrict__ x,
                                               const float* __restrict__ W,
                                               const float* __restrict__ Wl,
                                               double* __restrict__ w_d,
                                               float* __restrict__ gp){
  __shared__ float wl[16][128];
  __shared__ float il[128][65];
  __shared__ double part[4][64];
  int tid = threadIdx.x;
  int blk = blockIdx.x;
  if (blk >= 576){                                 // colsum Wl -> w_d
    int lane = tid & 63, ty = tid >> 6;
    int h = (blk - 576)*64 + lane;
    double acc = 0.0;
    for (int j = ty*128; j < ty*128 + 128; ++j) acc += (double)Wl[(size_t)j*HH + h];
    part[ty][lane] = acc;
    __syncthreads();
    if (ty == 0) w_d[h] = part[0][lane] + part[1][lane] + part[2][lane] + part[3][lane];
    return;
  }
  int rg = blk % 288, kc = blk / 288;
  int r0 = rg*16;                                  // [0, 4608)
  int s  = r0 / G3H;
  int g0 = r0 - s*G3H;
  int k0 = kc*128;
  const float* Wbase = W + (size_t)s*((size_t)G3H*IW) + (size_t)g0*IW + k0;
  for (int q = tid; q < 16*32; q += 256){
    int r = q >> 5, i4 = q & 31;
    *(float4*)&wl[r][i4*4] = *(const float4*)(Wbase + (size_t)r*IW + i4*4);
  }
  for (int q = tid; q < 64*32; q += 256){          // stage x[b][0][k0..k0+128) -> il[k][b]
    int row = q >> 5, f4 = q & 31;
    float4 v = *(const float4*)(x + (size_t)row*TT*IW + k0 + f4*4);
    il[f4*4+0][row] = v.x; il[f4*4+1][row] = v.y;
    il[f4*4+2][row] = v.z; il[f4*4+3][row] = v.w;
  }
  __syncthreads();
  int lane = tid & 63, wv = tid >> 6;
  int j = wv*4;
  const float4* w0 = (const float4*)wl[j];
  const float4* w1 = (const float4*)wl[j+1];
  const float4* w2 = (const float4*)wl[j+2];
  const float4* w3 = (const float4*)wl[j+3];
  float a0=0.f, a1=0.f, a2=0.f, a3=0.f;
  #pragma unroll 8
  for (int k4 = 0; k4 < 32; ++k4){
    float x0 = il[k4*4+0][lane];
    float x1 = il[k4*4+1][lane];
    float x2 = il[k4*4+2][lane];
    float x3 = il[k4*4+3][lane];
    float4 wa = w0[k4], wb = w1[k4], wc = w2[k4], wd = w3[k4];
    a0 += wa.x*x0 + wa.y*x1 + wa.z*x2 + wa.w*x3;
    a1 += wb.x*x0 + wb.y*x1 + wb.z*x2 + wb.w*x3;
    a2 += wc.x*x0 + wc.y*x1 + wc.z*x2 + wc.w*x3;
    a3 += wd.x*x0 + wd.y*x1 + wd.z*x2 + wd.w*x3;
  }
  float* op = gp + ((size_t)kc*4608 + r0 + j)*64 + lane;
  op[0] = a0; op[64] = a1; op[128] = a2; op[192] = a3;
}

// ---------- K-split gates GEMM (layers 1,2): W staged in LDS, in from global ----------
template<int K>
__global__ __launch_bounds__(256) void gates_part2(const float* __restrict__ W, long wS,
                                                   const float* __restrict__ in, int inS,
                                                   float* __restrict__ gp){
  __shared__ float wl[16][128];
  int tid = threadIdx.x;
  int rg = blockIdx.x % 288;
  int kc = blockIdx.x / 288;
  int r0 = rg*16;                       // [0, 4608)
  int s  = r0 / G3H;
  int g0 = r0 - s*G3H;
  int k0 = kc*128;
  const float* Wbase = W + (size_t)s*wS + (size_t)g0*K + k0;
  for (int q = tid; q < 16*32; q += 256){
    int r = q >> 5, i4 = q & 31;
    *(float4*)&wl[r][i4*4] = *(const float4*)(Wbase + (size_t)r*K + i4*4);
  }
  __syncthreads();
  int lane = tid & 63, wv = tid >> 6;
  int j = wv*4;
  const float4* w0 = (const float4*)wl[j];
  const float4* w1 = (const float4*)wl[j+1];
  const float4* w2 = (const float4*)wl[j+2];
  const float4* w3 = (const float4*)wl[j+3];
  const float* ip = in + (size_t)s*inS + (size_t)k0*64 + lane;
  float a0=0.f, a1=0.f, a2=0.f, a3=0.f;
  #pragma unroll 8
  for (int k4 = 0; k4 < 32; ++k4){
    float x0 = ip[(k4*4+0)*64];
    float x1 = ip[(k4*4+1)*64];
    float x2 = ip[(k4*4+2)*64];
    float x3 = ip[(k4*4+3)*64];
    float4 wa = w0[k4], wb = w1[k4], wc = w2[k4], wd = w3[k4];
    a0 += wa.x*x0 + wa.y*x1 + wa.z*x2 + wa.w*x3;
    a1 += wb.x*x0 + wb.y*x1 + wb.z*x2 + wb.w*x3;
    a2 += wc.x*x0 + wc.y*x1 + wc.z*x2 + wc.w*x3;
    a3 += wd.x*x0 + wd.y*x1 + wd.z*x2 + wd.w*x3;
  }
  float* op = gp + ((size_t)kc*4608 + r0 + j)*64 + lane;
  op[0] = a0; op[64] = a1; op[128] = a2; op[192] = a3;
}

// ---------- partial-reduce + GRU activation ----------
template<int NKC>
__global__ __launch_bounds__(256) void gru_act(const float* __restrict__ gp,
                                               const float* __restrict__ bih, long bihS,
                                               const float* __restrict__ bhh, long bhhS,
                                               float* __restrict__ h_all,
                                               float* __restrict__ hT_out, int writeHT, int l){
  int idx = blockIdx.x*256 + threadIdx.x;          // [0, 98304)
  int b = idx & 63;
  int h = (idx >> 6) & 511;
  int s = idx >> 15;
  size_t r = (size_t)s*G3H;
  float gr=0.f, gz=0.f, gn=0.f;
  #pragma unroll
  for (int kc = 0; kc < NKC; ++kc){
    const float* p = gp + (size_t)kc*294912;
    gr += p[(r + h)*64 + b];
    gz += p[(r + 512 + h)*64 + b];
    gn += p[(r + 1024 + h)*64 + b];
  }
  const float* bi = bih + (size_t)s*bihS;
  const float* bh = bhh + (size_t)s*bhhS;
  float rr = 1.f/(1.f + expf(-(gr + bi[h] + bh[h])));
  float zz = 1.f/(1.f + expf(-(gz + bi[512+h] + bh[512+h])));
  float nn = tanhf(gn + bi[1024+h] + rr*bh[1024+h]);
  float hv = (1.f - zz)*nn;
  h_all[(((size_t)s*BB + b)*3 + l)*HH + h] = hv;
  if (writeHT) hT_out[((size_t)s*HH + h)*BB + b] = hv;
}

// ---------- dots: one block per (s,b,l) row, 4-wave h-split ----------
__global__ __launch_bounds__(256) void dots2w(const float* __restrict__ h_all,
                                              const double* __restrict__ w_d,
                                              const float* __restrict__ Ws,
                                              double* __restrict__ score_d,
                                              double* __restrict__ dmat_d){
  __shared__ double red[4][4];
  int row = blockIdx.x;                            // [0, 576)
  int tid = threadIdx.x, lane = tid & 63, wv = tid >> 6;
  const float* hp = h_all + (size_t)row*HH;
  double a0=0.0, a1=0.0, a2=0.0, a3=0.0;
  #pragma unroll
  for (int jj = 0; jj < 2; ++jj){
    int h = wv*128 + jj*64 + lane;
    double hv = (double)hp[h];
    a0 += hv * w_d[h];
    a1 += hv * (double)Ws[h];
    a2 += hv * (double)Ws[768 + h];
    a3 += hv * (double)Ws[1536 + h];
  }
  for (int m = 32; m; m >>= 1){
    a0 += dshfl_xor(a0,m); a1 += dshfl_xor(a1,m);
    a2 += dshfl_xor(a2,m); a3 += dshfl_xor(a3,m);
  }
  if (lane == 0){ red[wv][0]=a0; red[wv][1]=a1; red[wv][2]=a2; red[wv][3]=a3; }
  __syncthreads();
  if (tid == 0){
    score_d[row]    = red[0][0]+red[1][0]+red[2][0]+red[3][0];
    dmat_d[row*3+0] = red[0][1]+red[1][1]+red[2][1]+red[3][1];
    dmat_d[row*3+1] = red[0][2]+red[1][2]+red[2][2]+red[3][2];
    dmat_d[row*3+2] = red[0][3]+red[1][3]+red[2][3]+red[3][3];
  }
}

// ---------- fused fold + xdot + softmax-sums: block t, 192 threads ----------
__global__ __launch_bounds__(192) void sums_x(const float* __restrict__ x,
                                              const float* __restrict__ Ws,
                                              const double* __restrict__ score_d,
                                              const double* __restrict__ dmat_d,
                                              const float* __restrict__ bs,
                                              int* __restrict__ Lint){
  __shared__ float xl[64*257];
  __shared__ float wsl[3*256];
  __shared__ double dl[3*64];
  __shared__ double P1L[576];
  int t = blockIdx.x, tid = threadIdx.x;
  int lane = tid & 63, w = tid >> 6;               // w = s (fold) / c (dot) / cur (final)
  for (int i = tid; i < 768; i += 192) wsl[i] = Ws[(i >> 8)*768 + 512 + (i & 255)];
  for (int q = tid; q < 4096; q += 192){           // stage x[:,t,:] via float4
    int r = q >> 6, i4 = q & 63;
    float4 v = *(const float4*)(x + ((size_t)r*TT + t)*IW + i4*4);
    float* dst = &xl[r*257 + i4*4];
    dst[0]=v.x; dst[1]=v.y; dst[2]=v.z; dst[3]=v.w;
  }
  {  // fold (redundant per block, cheap): P1L[s][c][b]
    int base = w*192 + lane*3;
    double s0 = score_d[base], s1 = score_d[base+1], s2 = score_d[base+2];
    double m = fmax(s0, fmax(s1, s2));
    double e0 = exp(s0-m), e1 = exp(s1-m), e2 = exp(s2-m);
    double inv = 1.0/(e0+e1+e2);
    e0 *= inv; e1 *= inv; e2 *= inv;
    for (int c = 0; c < 3; ++c){
      double v = e0*dmat_d[base*3 + c] + e1*dmat_d[(base+1)*3 + c] + e2*dmat_d[(base+2)*3 + c];
      P1L[(w*3 + c)*64 + lane] = v + (double)bs[c];
    }
  }
  __syncthreads();
  {
    const float* xr = &xl[lane*257];
    const float* wr = &wsl[w*256];
    double acc = 0.0;
    #pragma unroll 8
    for (int i = 0; i < 256; ++i) acc += (double)xr[i] * (double)wr[i];
    dl[w*64 + lane] = acc;
  }
  __syncthreads();
  double l0 = P1L[(w*3+0)*64 + lane] + dl[0*64 + lane];
  double l1 = P1L[(w*3+1)*64 + lane] + dl[1*64 + lane];
  double l2 = P1L[(w*3+2)*64 + lane] + dl[2*64 + lane];
  double m = fmax(l0, fmax(l1, l2));
  double e0 = exp(l0-m), e1 = exp(l1-m), e2 = exp(l2-m);
  double inv = 1.0/(e0+e1+e2);
  e0 *= inv; e1 *= inv; e2 *= inv;
  for (int mm = 32; mm; mm >>= 1){
    e0 += dshfl_xor(e0, mm); e1 += dshfl_xor(e1, mm); e2 += dshfl_xor(e2, mm);
  }
  if (lane == 0){
    int q0 = (int)lrintf(fmaxf(log2f((float)e0), -1500.f) * 1048576.0f);
    int q1 = (int)lrintf(fmaxf(log2f((float)e1), -1500.f) * 1048576.0f);
    int q2 = (int)lrintf(fmaxf(log2f((float)e2), -1500.f) * 1048576.0f);
    int* p = Lint + (size_t)t*12 + w*3;
    p[0] = (q0 & ~3) | 2;     // embed idx = 2-c so exact ties pick smallest c
    p[1] = (q1 & ~3) | 1;
    p[2] = (q2 & ~3) | 0;
  }
}

// ---------- scan7: data pre-hoisted to VGPRs, per-step readlane (off-chain) + SALU chain ----------
// v[g][j]: lane l holds Lint[(g*64+l)*12 + j]. State (idx, a0..a2, word) is lane-invariant -> SGPRs.
#define SCANSTEP(G, LQ) do {                                        \
  int x0 = __builtin_amdgcn_readlane(v[G][0], (LQ));                \
  int x1 = __builtin_amdgcn_readlane(v[G][1], (LQ));                \
  int x2 = __builtin_amdgcn_readlane(v[G][2], (LQ));                \
  int x3 = __builtin_amdgcn_readlane(v[G][3], (LQ));                \
  int x4 = __builtin_amdgcn_readlane(v[G][4], (LQ));                \
  int x5 = __builtin_amdgcn_readlane(v[G][5], (LQ));                \
  int x6 = __builtin_amdgcn_readlane(v[G][6], (LQ));                \
  int x7 = __builtin_amdgcn_readlane(v[G][7], (LQ));                \
  int x8 = __builtin_amdgcn_readlane(v[G][8], (LQ));                \
  int L0 = (idx==2)?x0:((idx==1)?x3:x6);                            \
  int L1 = (idx==2)?x1:((idx==1)?x4:x7);                            \
  int L2 = (idx==2)?x2:((idx==1)?x5:x8);                            \
  int u0 = L0-a0, u1 = L1-a1, u2 = L2-a2;                           \
  int bm = u0 > u1 ? u0 : u1; bm = bm > u2 ? bm : u2;               \
  idx = bm & 3;                                                     \
  a0 += (idx==2) ? PEN1 : 0;                                        \
  a1 += (idx==1) ? PEN1 : 0;                                        \
  a2 += (idx==0) ? PEN1 : 0;                                        \
  word |= (unsigned)(2 - idx) << (2*k);                             \
} while(0)

#define SCANGRP(G) do {                                             \
  for (int q = 0; q < 4; ++q){                                      \
    unsigned word = 0u;                                             \
    _Pragma("unroll 4")                                             \
    for (int k = 0; k < 16; ++k){                                   \
      int lq = q*16 + k;                                            \
      if ((G) == 0 && lq == 0){ continue; }   /* t=0: cur=0 */      \
      SCANSTEP(G, lq);                                              \
    }                                                               \
    if (lane == 0) curpack[(G)*4 + q] = word;                       \
  }                                                                 \
} while(0)

__global__ __launch_bounds__(64, 1) void scan7(const int* __restrict__ Lint,
                                               unsigned* __restrict__ curpack){
  int lane = threadIdx.x;
  int v[8][9];
  #pragma unroll
  for (int g = 0; g < 8; ++g){
    const int* p = Lint + ((size_t)(g*64 + lane))*12;
    #pragma unroll
    for (int j = 0; j < 9; ++j) v[g][j] = p[j];
  }
  int a0 = PEN1, a1 = 0, a2 = 0, idx = 2;          // pen exps [1,0,0], cur=0 -> idx=2
  SCANGRP(0); SCANGRP(1); SCANGRP(2); SCANGRP(3);
  SCANGRP(4); SCANGRP(5); SCANGRP(6); SCANGRP(7);
}

// ---------- outputs (f32), fused; cur from 2-bit packed words ----------
__global__ __launch_bounds__(256) void out_all(const float* __restrict__ h_all,
                                               const unsigned* __restrict__ curpack,
                                               float* __restrict__ out){
  int blk = blockIdx.x;
  if (blk < 512){
    int t = blk;
    int cur = (int)((curpack[t >> 4] >> ((t & 15)*2)) & 3u);
    const float* base = h_all + (size_t)cur*98304 + 2*HH;  // [cur][b][2][:], b-stride 1536
    int tid = threadIdx.x;
    for (int k = 0; k < 32; ++k){
      int e4 = (k*256 + tid)*4;                            // [0, 32768)
      int b = e4 >> 9, h = e4 & 511;
      float4 v = *(const float4*)(base + (size_t)b*1536 + h);
      *(float4*)(&out[((size_t)b*TT + t)*HH + h]) = v;
    }
  } else {
    int cur = (int)((curpack[31] >> 30) & 3u);
    int e4 = ((blk - 512)*256 + threadIdx.x)*4;            // [0, 98304)
    float4 v = *(const float4*)(h_all + (size_t)cur*98304 + e4);
    *(float4*)(&out[(size_t)BB*TT*HH + e4]) = v;
  }
}

extern "C" void kernel_launch(void* const* d_in, const int* in_sizes, int n_in,
                              void* d_out, int out_size, void* d_ws, size_t ws_size,
                              hipStream_t stream){
  const float* x    = (const float*)d_in[0];
  const float* Wl   = (const float*)d_in[1];
  // d_in[2] = bl : constant over L inside softmax -> cancels; unused
  const float* Ws   = (const float*)d_in[3];
  const float* bs   = (const float*)d_in[4];
  const float* Wih0 = (const float*)d_in[5];
  const float* bih0 = (const float*)d_in[6];
  const float* bhh0 = (const float*)d_in[7];
  const float* WihL = (const float*)d_in[8];
  const float* bihL = (const float*)d_in[9];
  const float* bhhL = (const float*)d_in[10];
  float* out = (float*)d_out;

  // ---- sentinels ----
  static const int exp_sizes[11] = {8388608, 262144, 512, 2304, 3,
                                    1179648, 4608, 4608, 4718592, 9216, 9216};
  int bad = 0;
  if (n_in != 11) bad = 13;
  else {
    for (int i = 0; i < 11; ++i) if (in_sizes[i] != exp_sizes[i]) { bad = i + 1; break; }
  }
  if (!bad && out_size != 16875520) bad = 12;
  if (bad){
    sentinel_k<<<dim3(1), dim3(1), 0, stream>>>(out, 1048576.0f * (float)bad);
    return;
  }
  if (ws_size < 1292416){
    sentinel_k<<<dim3(1), dim3(1), 0, stream>>>(out, 3.0e7f + (float)(ws_size >> 6));
    return;
  }

  // ---- ws layout ----
  double*   w_d     = (double*)d_ws;              // 512 f64
  double*   score_d = w_d + 512;                  // 576 f64
  double*   dmat_d  = score_d + 576;              // 1728 f64
  int*      Lint    = (int*)(dmat_d + 1728);      // 6144 i32
  float*    h_all   = (float*)(Lint + 6144);      // 294912 f32
  float*    x0T     = h_all + 294912;             // 16384 f32 (unused hole, kept for layout stability)
  unsigned* curpack = (unsigned*)(x0T + 16384);   // 32 u32

  // ---- big scratch in d_out tail (dead before out_all writes) ----
  char* outb = (char*)d_out;
  float* gip = (float*)(outb + 50331648);         // [4][4608][64] f32 = 4,718,592 B
  float* hT0 = gip + 1179648;                     // [3][512][64]  f32 =   393,216 B
  float* hT1 = hT0 + 98304;                       // same

  // GRU stack: K-split partial GEMM + activation (layer 0 self-stages x, + colsum tail)
  gates0x         <<<dim3(584),  dim3(256), 0, stream>>>(x, Wih0, Wl, w_d, gip);
  gru_act<2>      <<<dim3(384),  dim3(256), 0, stream>>>(gip, bih0, G3H, bhh0, G3H, h_all, hT0, 1, 0);
  gates_part2<512><<<dim3(1152), dim3(256), 0, stream>>>(WihL, (long)2*G3H*HH, hT0, HH*BB, gip);
  gru_act<4>      <<<dim3(384),  dim3(256), 0, stream>>>(gip, bihL, 2*G3H, bhhL, 2*G3H, h_all, hT1, 1, 1);
  gates_part2<512><<<dim3(1152), dim3(256), 0, stream>>>(WihL + (size_t)G3H*HH, (long)2*G3H*HH, hT1, HH*BB, gip);
  gru_act<4>      <<<dim3(384),  dim3(256), 0, stream>>>(gip, bihL + G3H, 2*G3H, bhhL + G3H, 2*G3H, h_all, hT0, 0, 2);

  dots2w<<<dim3(576), dim3(256), 0, stream>>>(h_all, w_d, Ws, score_d, dmat_d);
  sums_x<<<dim3(512), dim3(192), 0, stream>>>(x, Ws, score_d, dmat_d, bs, Lint);

  scan7<<<dim3(1), dim3(64), 0, stream>>>(Lint, curpack);

  out_all<<<dim3(608), dim3(256), 0, stream>>>(h_all, curpack, out);
}

// Round 14
// 121.076 us; speedup vs baseline: 1.1081x; 1.1081x over previous
//
#include <hip/hip_runtime.h>
#include <hip/hip_bf16.h>
#include <math.h>

#define BB 64
#define TT 512
#define IW 256
#define HH 512
#define G3H 1536
#define PEN1 (1<<20)

__device__ __forceinline__ double dshfl_xor(double v, int m){
  int2 a = *(int2*)&v;
  a.x = __shfl_xor(a.x, m, 64);
  a.y = __shfl_xor(a.y, m, 64);
  return *(double*)&a;
}

__global__ void sentinel_k(float* out, float v){ out[0] = v; }

// ---------- layer-0 gates: scalar W loads + LDS-transposed x-slice; colsum tail blocks ----------
__global__ __launch_bounds__(256) void gates0x(const float* __restrict__ x,
                                               const float* __restrict__ W,
                                               const float* __restrict__ Wl,
                                               double* __restrict__ w_d,
                                               float* __restrict__ gp){
  __shared__ float il[128][65];
  __shared__ double part[4][64];
  int tid = threadIdx.x;
  int blk = blockIdx.x;
  if (blk >= 576){                                 // colsum Wl -> w_d
    int lane = tid & 63, ty = tid >> 6;
    int h = (blk - 576)*64 + lane;
    double acc = 0.0;
    for (int j = ty*128; j < ty*128 + 128; ++j) acc += (double)Wl[(size_t)j*HH + h];
    part[ty][lane] = acc;
    __syncthreads();
    if (ty == 0) w_d[h] = part[0][lane] + part[1][lane] + part[2][lane] + part[3][lane];
    return;
  }
  int rg = blk % 288, kc = blk / 288;
  int r0 = rg*16;                                  // [0, 4608)
  int s  = r0 / G3H;
  int g0 = r0 - s*G3H;
  int k0 = kc*128;
  for (int q = tid; q < 64*32; q += 256){          // stage x[b][0][k0..k0+128) -> il[k][b]
    int row = q >> 5, f4 = q & 31;
    float4 v = *(const float4*)(x + (size_t)row*TT*IW + k0 + f4*4);
    il[f4*4+0][row] = v.x; il[f4*4+1][row] = v.y;
    il[f4*4+2][row] = v.z; il[f4*4+3][row] = v.w;
  }
  __syncthreads();
  int lane = tid & 63;
  int wv = __builtin_amdgcn_readfirstlane(tid >> 6);  // wave-uniform -> scalar W path
  int j = wv*4;
  const float* w0 = W + (size_t)s*((size_t)G3H*IW) + (size_t)(g0 + j)*IW + k0;
  const float* w1 = w0 + IW;
  const float* w2 = w1 + IW;
  const float* w3 = w2 + IW;
  float a0=0.f, a1=0.f, a2=0.f, a3=0.f;
  #pragma unroll 8
  for (int k4 = 0; k4 < 32; ++k4){
    float x0 = il[k4*4+0][lane];
    float x1 = il[k4*4+1][lane];
    float x2 = il[k4*4+2][lane];
    float x3 = il[k4*4+3][lane];
    int k = k4*4;
    a0 += w0[k]*x0 + w0[k+1]*x1 + w0[k+2]*x2 + w0[k+3]*x3;
    a1 += w1[k]*x0 + w1[k+1]*x1 + w1[k+2]*x2 + w1[k+3]*x3;
    a2 += w2[k]*x0 + w2[k+1]*x1 + w2[k+2]*x2 + w2[k+3]*x3;
    a3 += w3[k]*x0 + w3[k+1]*x1 + w3[k+2]*x2 + w3[k+3]*x3;
  }
  float* op = gp + ((size_t)kc*4608 + r0 + j)*64 + lane;
  op[0] = a0; op[64] = a1; op[128] = a2; op[192] = a3;
}

// ---------- K-split gates GEMM (layers 1,2): scalar W loads, in from global ----------
template<int K>
__global__ __launch_bounds__(256) void gates_part2(const float* __restrict__ W, long wS,
                                                   const float* __restrict__ in, int inS,
                                                   float* __restrict__ gp){
  int tid = threadIdx.x;
  int rg = blockIdx.x % 288;
  int kc = blockIdx.x / 288;
  int r0 = rg*16;                       // [0, 4608)
  int s  = r0 / G3H;
  int g0 = r0 - s*G3H;
  int k0 = kc*128;
  int lane = tid & 63;
  int wv = __builtin_amdgcn_readfirstlane(tid >> 6);  // wave-uniform -> scalar W path
  int j = wv*4;
  const float* w0 = W + (size_t)s*wS + (size_t)(g0 + j)*K + k0;
  const float* w1 = w0 + K;
  const float* w2 = w1 + K;
  const float* w3 = w2 + K;
  const float* ip = in + (size_t)s*inS + (size_t)k0*64 + lane;
  float a0=0.f, a1=0.f, a2=0.f, a3=0.f;
  #pragma unroll 8
  for (int k4 = 0; k4 < 32; ++k4){
    float x0 = ip[(k4*4+0)*64];
    float x1 = ip[(k4*4+1)*64];
    float x2 = ip[(k4*4+2)*64];
    float x3 = ip[(k4*4+3)*64];
    int k = k4*4;
    a0 += w0[k]*x0 + w0[k+1]*x1 + w0[k+2]*x2 + w0[k+3]*x3;
    a1 += w1[k]*x0 + w1[k+1]*x1 + w1[k+2]*x2 + w1[k+3]*x3;
    a2 += w2[k]*x0 + w2[k+1]*x1 + w2[k+2]*x2 + w2[k+3]*x3;
    a3 += w3[k]*x0 + w3[k+1]*x1 + w3[k+2]*x2 + w3[k+3]*x3;
  }
  float* op = gp + ((size_t)kc*4608 + r0 + j)*64 + lane;
  op[0] = a0; op[64] = a1; op[128] = a2; op[192] = a3;
}

// ---------- partial-reduce + GRU activation ----------
template<int NKC>
__global__ __launch_bounds__(256) void gru_act(const float* __restrict__ gp,
                                               const float* __restrict__ bih, long bihS,
                                               const float* __restrict__ bhh, long bhhS,
                                               float* __restrict__ h_all,
                                               float* __restrict__ hT_out, int writeHT, int l){
  int idx = blockIdx.x*256 + threadIdx.x;          // [0, 98304)
  int b = idx & 63;
  int h = (idx >> 6) & 511;
  int s = idx >> 15;
  size_t r = (size_t)s*G3H;
  float gr=0.f, gz=0.f, gn=0.f;
  #pragma unroll
  for (int kc = 0; kc < NKC; ++kc){
    const float* p = gp + (size_t)kc*294912;
    gr += p[(r + h)*64 + b];
    gz += p[(r + 512 + h)*64 + b];
    gn += p[(r + 1024 + h)*64 + b];
  }
  const float* bi = bih + (size_t)s*bihS;
  const float* bh = bhh + (size_t)s*bhhS;
  float rr = 1.f/(1.f + expf(-(gr + bi[h] + bh[h])));
  float zz = 1.f/(1.f + expf(-(gz + bi[512+h] + bh[512+h])));
  float nn = tanhf(gn + bi[1024+h] + rr*bh[1024+h]);
  float hv = (1.f - zz)*nn;
  h_all[(((size_t)s*BB + b)*3 + l)*HH + h] = hv;
  if (writeHT) hT_out[((size_t)s*HH + h)*BB + b] = hv;
}

// ---------- dots: one block per (s,b,l) row, 4-wave h-split ----------
__global__ __launch_bounds__(256) void dots2w(const float* __restrict__ h_all,
                                              const double* __restrict__ w_d,
                                              const float* __restrict__ Ws,
                                              double* __restrict__ score_d,
                                              double* __restrict__ dmat_d){
  __shared__ double red[4][4];
  int row = blockIdx.x;                            // [0, 576)
  int tid = threadIdx.x, lane = tid & 63, wv = tid >> 6;
  const float* hp = h_all + (size_t)row*HH;
  double a0=0.0, a1=0.0, a2=0.0, a3=0.0;
  #pragma unroll
  for (int jj = 0; jj < 2; ++jj){
    int h = wv*128 + jj*64 + lane;
    double hv = (double)hp[h];
    a0 += hv * w_d[h];
    a1 += hv * (double)Ws[h];
    a2 += hv * (double)Ws[768 + h];
    a3 += hv * (double)Ws[1536 + h];
  }
  for (int m = 32; m; m >>= 1){
    a0 += dshfl_xor(a0,m); a1 += dshfl_xor(a1,m);
    a2 += dshfl_xor(a2,m); a3 += dshfl_xor(a3,m);
  }
  if (lane == 0){ red[wv][0]=a0; red[wv][1]=a1; red[wv][2]=a2; red[wv][3]=a3; }
  __syncthreads();
  if (tid == 0){
    score_d[row]    = red[0][0]+red[1][0]+red[2][0]+red[3][0];
    dmat_d[row*3+0] = red[0][1]+red[1][1]+red[2][1]+red[3][1];
    dmat_d[row*3+1] = red[0][2]+red[1][2]+red[2][2]+red[3][2];
    dmat_d[row*3+2] = red[0][3]+red[1][3]+red[2][3]+red[3][3];
  }
}

// ---------- fused fold + xdot + softmax-sums: block t, 192 threads ----------
__global__ __launch_bounds__(192) void sums_x(const float* __restrict__ x,
                                              const float* __restrict__ Ws,
                                              const double* __restrict__ score_d,
                                              const double* __restrict__ dmat_d,
                                              const float* __restrict__ bs,
                                              int* __restrict__ Lint){
  __shared__ float xl[64*257];
  __shared__ float wsl[3*256];
  __shared__ double dl[3*64];
  __shared__ double P1L[576];
  int t = blockIdx.x, tid = threadIdx.x;
  int lane = tid & 63, w = tid >> 6;               // w = s (fold) / c (dot) / cur (final)
  for (int i = tid; i < 768; i += 192) wsl[i] = Ws[(i >> 8)*768 + 512 + (i & 255)];
  for (int q = tid; q < 4096; q += 192){           // stage x[:,t,:] via float4
    int r = q >> 6, i4 = q & 63;
    float4 v = *(const float4*)(x + ((size_t)r*TT + t)*IW + i4*4);
    float* dst = &xl[r*257 + i4*4];
    dst[0]=v.x; dst[1]=v.y; dst[2]=v.z; dst[3]=v.w;
  }
  {  // fold (redundant per block, cheap): P1L[s][c][b]
    int base = w*192 + lane*3;
    double s0 = score_d[base], s1 = score_d[base+1], s2 = score_d[base+2];
    double m = fmax(s0, fmax(s1, s2));
    double e0 = exp(s0-m), e1 = exp(s1-m), e2 = exp(s2-m);
    double inv = 1.0/(e0+e1+e2);
    e0 *= inv; e1 *= inv; e2 *= inv;
    for (int c = 0; c < 3; ++c){
      double v = e0*dmat_d[base*3 + c] + e1*dmat_d[(base+1)*3 + c] + e2*dmat_d[(base+2)*3 + c];
      P1L[(w*3 + c)*64 + lane] = v + (double)bs[c];
    }
  }
  __syncthreads();
  {
    const float* xr = &xl[lane*257];
    const float* wr = &wsl[w*256];
    double acc = 0.0;
    #pragma unroll 8
    for (int i = 0; i < 256; ++i) acc += (double)xr[i] * (double)wr[i];
    dl[w*64 + lane] = acc;
  }
  __syncthreads();
  double l0 = P1L[(w*3+0)*64 + lane] + dl[0*64 + lane];
  double l1 = P1L[(w*3+1)*64 + lane] + dl[1*64 + lane];
  double l2 = P1L[(w*3+2)*64 + lane] + dl[2*64 + lane];
  double m = fmax(l0, fmax(l1, l2));
  double e0 = exp(l0-m), e1 = exp(l1-m), e2 = exp(l2-m);
  double inv = 1.0/(e0+e1+e2);
  e0 *= inv; e1 *= inv; e2 *= inv;
  for (int mm = 32; mm; mm >>= 1){
    e0 += dshfl_xor(e0, mm); e1 += dshfl_xor(e1, mm); e2 += dshfl_xor(e2, mm);
  }
  if (lane == 0){
    int q0 = (int)lrintf(fmaxf(log2f((float)e0), -1500.f) * 1048576.0f);
    int q1 = (int)lrintf(fmaxf(log2f((float)e1), -1500.f) * 1048576.0f);
    int q2 = (int)lrintf(fmaxf(log2f((float)e2), -1500.f) * 1048576.0f);
    int* p = Lint + (size_t)t*12 + w*3;
    p[0] = (q0 & ~3) | 2;     // embed idx = 2-c so exact ties pick smallest c
    p[1] = (q1 & ~3) | 1;
    p[2] = (q2 & ~3) | 0;
  }
}

// ---------- VALU scan (round-12 measured-best): idx-based state, 8-deep rotation ----------
#define LOADI(X0,X1,X2, tt) do { int _t = (tt); if (_t > 511) _t = 511;  \
  const int4* _p = (const int4*)&lds[_t*12]; X0=_p[0]; X1=_p[1]; X2=_p[2]; } while(0)

#define STEPI(S0,S1,S2, kk) do {                                \
  int L0 = (idx==2)?S0.x:((idx==1)?S0.w:S1.z);                  \
  int L1 = (idx==2)?S0.y:((idx==1)?S1.x:S1.w);                  \
  int L2 = (idx==2)?S0.z:((idx==1)?S1.y:S2.x);                  \
  int v0 = L0-a0, v1 = L1-a1, v2 = L2-a2;                       \
  int bm = v0 > v1 ? v0 : v1; bm = bm > v2 ? bm : v2;           \
  idx = bm & 3;                                                 \
  a0 += (idx==2) ? PEN1 : 0;                                    \
  a1 += (idx==1) ? PEN1 : 0;                                    \
  a2 += (idx==0) ? PEN1 : 0;                                    \
  word |= (unsigned)(2 - idx) << (2*(kk)); } while(0)

__global__ __launch_bounds__(64, 1) void scan6(const int* __restrict__ Lint,
                                               unsigned* __restrict__ curpack){
  __shared__ int lds[TT*12];
  int lane = threadIdx.x;
  for (int i = lane*4; i < TT*12; i += 256)
    *(int4*)&lds[i] = *(const int4*)&Lint[i];
  __syncthreads();
  int a0 = PEN1, a1 = 0, a2 = 0, idx = 2;
  int4 A0,A1,A2,B0,B1,B2,C0,C1,C2,D0,D1,D2,E0,E1,E2,F0,F1,F2,G0,G1,G2,H0,H1,H2;
  LOADI(A0,A1,A2, 0); LOADI(B0,B1,B2, 1); LOADI(C0,C1,C2, 2); LOADI(D0,D1,D2, 3);
  LOADI(E0,E1,E2, 4); LOADI(F0,F1,F2, 5); LOADI(G0,G1,G2, 6); LOADI(H0,H1,H2, 7);
  for (int base = 0; base < 512; base += 16){
    unsigned word = 0u;
    if (base){ STEPI(A0,A1,A2, 0); }            // t=0: cur=0, bits stay 0
    LOADI(A0,A1,A2, base+8);
    STEPI(B0,B1,B2, 1);   LOADI(B0,B1,B2, base+9);
    STEPI(C0,C1,C2, 2);   LOADI(C0,C1,C2, base+10);
    STEPI(D0,D1,D2, 3);   LOADI(D0,D1,D2, base+11);
    STEPI(E0,E1,E2, 4);   LOADI(E0,E1,E2, base+12);
    STEPI(F0,F1,F2, 5);   LOADI(F0,F1,F2, base+13);
    STEPI(G0,G1,G2, 6);   LOADI(G0,G1,G2, base+14);
    STEPI(H0,H1,H2, 7);   LOADI(H0,H1,H2, base+15);
    STEPI(A0,A1,A2, 8);   LOADI(A0,A1,A2, base+16);
    STEPI(B0,B1,B2, 9);   LOADI(B0,B1,B2, base+17);
    STEPI(C0,C1,C2, 10);  LOADI(C0,C1,C2, base+18);
    STEPI(D0,D1,D2, 11);  LOADI(D0,D1,D2, base+19);
    STEPI(E0,E1,E2, 12);  LOADI(E0,E1,E2, base+20);
    STEPI(F0,F1,F2, 13);  LOADI(F0,F1,F2, base+21);
    STEPI(G0,G1,G2, 14);  LOADI(G0,G1,G2, base+22);
    STEPI(H0,H1,H2, 15);  LOADI(H0,H1,H2, base+23);
    if (lane == 0) curpack[base >> 4] = word;
  }
}

// ---------- outputs (f32), fused; cur from 2-bit packed words ----------
__global__ __launch_bounds__(256) void out_all(const float* __restrict__ h_all,
                                               const unsigned* __restrict__ curpack,
                                               float* __restrict__ out){
  int blk = blockIdx.x;
  if (blk < 512){
    int t = blk;
    int cur = (int)((curpack[t >> 4] >> ((t & 15)*2)) & 3u);
    const float* base = h_all + (size_t)cur*98304 + 2*HH;  // [cur][b][2][:], b-stride 1536
    int tid = threadIdx.x;
    for (int k = 0; k < 32; ++k){
      int e4 = (k*256 + tid)*4;                            // [0, 32768)
      int b = e4 >> 9, h = e4 & 511;
      float4 v = *(const float4*)(base + (size_t)b*1536 + h);
      *(float4*)(&out[((size_t)b*TT + t)*HH + h]) = v;
    }
  } else {
    int cur = (int)((curpack[31] >> 30) & 3u);
    int e4 = ((blk - 512)*256 + threadIdx.x)*4;            // [0, 98304)
    float4 v = *(const float4*)(h_all + (size_t)cur*98304 + e4);
    *(float4*)(&out[(size_t)BB*TT*HH + e4]) = v;
  }
}

extern "C" void kernel_launch(void* const* d_in, const int* in_sizes, int n_in,
                              void* d_out, int out_size, void* d_ws, size_t ws_size,
                              hipStream_t stream){
  const float* x    = (const float*)d_in[0];
  const float* Wl   = (const float*)d_in[1];
  // d_in[2] = bl : constant over L inside softmax -> cancels; unused
  const float* Ws   = (const float*)d_in[3];
  const float* bs   = (const float*)d_in[4];
  const float* Wih0 = (const float*)d_in[5];
  const float* bih0 = (const float*)d_in[6];
  const float* bhh0 = (const float*)d_in[7];
  const float* WihL = (const float*)d_in[8];
  const float* bihL = (const float*)d_in[9];
  const float* bhhL = (const float*)d_in[10];
  float* out = (float*)d_out;

  // ---- sentinels ----
  static const int exp_sizes[11] = {8388608, 262144, 512, 2304, 3,
                                    1179648, 4608, 4608, 4718592, 9216, 9216};
  int bad = 0;
  if (n_in != 11) bad = 13;
  else {
    for (int i = 0; i < 11; ++i) if (in_sizes[i] != exp_sizes[i]) { bad = i + 1; break; }
  }
  if (!bad && out_size != 16875520) bad = 12;
  if (bad){
    sentinel_k<<<dim3(1), dim3(1), 0, stream>>>(out, 1048576.0f * (float)bad);
    return;
  }
  if (ws_size < 1292416){
    sentinel_k<<<dim3(1), dim3(1), 0, stream>>>(out, 3.0e7f + (float)(ws_size >> 6));
    return;
  }

  // ---- ws layout ----
  double*   w_d     = (double*)d_ws;              // 512 f64
  double*   score_d = w_d + 512;                  // 576 f64
  double*   dmat_d  = score_d + 576;              // 1728 f64
  int*      Lint    = (int*)(dmat_d + 1728);      // 6144 i32
  float*    h_all   = (float*)(Lint + 6144);      // 294912 f32
  float*    x0T     = h_all + 294912;             // 16384 f32 (unused hole, kept for layout stability)
  unsigned* curpack = (unsigned*)(x0T + 16384);   // 32 u32

  // ---- big scratch in d_out tail (dead before out_all writes) ----
  char* outb = (char*)d_out;
  float* gip = (float*)(outb + 50331648);         // [4][4608][64] f32 = 4,718,592 B
  float* hT0 = gip + 1179648;                     // [3][512][64]  f32 =   393,216 B
  float* hT1 = hT0 + 98304;                       // same

  // GRU stack: K-split partial GEMM (scalar W) + activation
  gates0x         <<<dim3(584),  dim3(256), 0, stream>>>(x, Wih0, Wl, w_d, gip);
  gru_act<2>      <<<dim3(384),  dim3(256), 0, stream>>>(gip, bih0, G3H, bhh0, G3H, h_all, hT0, 1, 0);
  gates_part2<512><<<dim3(1152), dim3(256), 0, stream>>>(WihL, (long)2*G3H*HH, hT0, HH*BB, gip);
  gru_act<4>      <<<dim3(384),  dim3(256), 0, stream>>>(gip, bihL, 2*G3H, bhhL, 2*G3H, h_all, hT1, 1, 1);
  gates_part2<512><<<dim3(1152), dim3(256), 0, stream>>>(WihL + (size_t)G3H*HH, (long)2*G3H*HH, hT1, HH*BB, gip);
  gru_act<4>      <<<dim3(384),  dim3(256), 0, stream>>>(gip, bihL + G3H, 2*G3H, bhhL + G3H, 2*G3H, h_all, hT0, 0, 2);

  dots2w<<<dim3(576), dim3(256), 0, stream>>>(h_all, w_d, Ws, score_d, dmat_d);
  sums_x<<<dim3(512), dim3(192), 0, stream>>>(x, Ws, score_d, dmat_d, bs, Lint);

  scan6<<<dim3(1), dim3(64), 0, stream>>>(Lint, curpack);

  out_all<<<dim3(608), dim3(256), 0, stream>>>(h_all, curpack, out);
}

// Round 15
// 116.684 us; speedup vs baseline: 1.1498x; 1.0376x over previous
//
#include <hip/hip_runtime.h>
#include <hip/hip_bf16.h>
#include <math.h>

#define BB 64
#define TT 512
#define IW 256
#define HH 512
#define G3H 1536
#define PEN1 (1<<20)

__device__ __forceinline__ double dshfl_xor(double v, int m){
  int2 a = *(int2*)&v;
  a.x = __shfl_xor(a.x, m, 64);
  a.y = __shfl_xor(a.y, m, 64);
  return *(double*)&a;
}

__global__ void sentinel_k(float* out, float v){ out[0] = v; }

// ---------- layer-0 gates (LDS W tile + LDS-transposed x-slice) + colsum tail ----------
__global__ __launch_bounds__(256) void gates0x(const float* __restrict__ x,
                                               const float* __restrict__ W,
                                               const float* __restrict__ Wl,
                                               double* __restrict__ w_d,
                                               float* __restrict__ gp){
  __shared__ float wl[16][128];
  __shared__ float il[128][65];
  __shared__ double part[4][64];
  int tid = threadIdx.x;
  int blk = blockIdx.x;
  if (blk >= 576){                                 // colsum Wl -> w_d
    int lane = tid & 63, ty = tid >> 6;
    int h = (blk - 576)*64 + lane;
    double acc = 0.0;
    for (int j = ty*128; j < ty*128 + 128; ++j) acc += (double)Wl[(size_t)j*HH + h];
    part[ty][lane] = acc;
    __syncthreads();
    if (ty == 0) w_d[h] = part[0][lane] + part[1][lane] + part[2][lane] + part[3][lane];
    return;
  }
  int rg = blk % 288, kc = blk / 288;
  int r0 = rg*16;                                  // [0, 4608)
  int s  = r0 / G3H;
  int g0 = r0 - s*G3H;
  int k0 = kc*128;
  const float* Wbase = W + (size_t)s*((size_t)G3H*IW) + (size_t)g0*IW + k0;
  for (int q = tid; q < 16*32; q += 256){
    int r = q >> 5, i4 = q & 31;
    *(float4*)&wl[r][i4*4] = *(const float4*)(Wbase + (size_t)r*IW + i4*4);
  }
  for (int q = tid; q < 64*32; q += 256){          // stage x[b][0][k0..k0+128) -> il[k][b]
    int row = q >> 5, f4 = q & 31;
    float4 v = *(const float4*)(x + (size_t)row*TT*IW + k0 + f4*4);
    il[f4*4+0][row] = v.x; il[f4*4+1][row] = v.y;
    il[f4*4+2][row] = v.z; il[f4*4+3][row] = v.w;
  }
  __syncthreads();
  int lane = tid & 63, wv = tid >> 6;
  int j = wv*4;
  const float4* w0 = (const float4*)wl[j];
  const float4* w1 = (const float4*)wl[j+1];
  const float4* w2 = (const float4*)wl[j+2];
  const float4* w3 = (const float4*)wl[j+3];
  float a0=0.f, a1=0.f, a2=0.f, a3=0.f;
  #pragma unroll 8
  for (int k4 = 0; k4 < 32; ++k4){
    float x0 = il[k4*4+0][lane];
    float x1 = il[k4*4+1][lane];
    float x2 = il[k4*4+2][lane];
    float x3 = il[k4*4+3][lane];
    float4 wa = w0[k4], wb = w1[k4], wc = w2[k4], wd = w3[k4];
    a0 += wa.x*x0 + wa.y*x1 + wa.z*x2 + wa.w*x3;
    a1 += wb.x*x0 + wb.y*x1 + wb.z*x2 + wb.w*x3;
    a2 += wc.x*x0 + wc.y*x1 + wc.z*x2 + wc.w*x3;
    a3 += wd.x*x0 + wd.y*x1 + wd.z*x2 + wd.w*x3;
  }
  float* op = gp + ((size_t)kc*4608 + r0 + j)*64 + lane;
  op[0] = a0; op[64] = a1; op[128] = a2; op[192] = a3;
}

// ---------- K-split gates GEMM (layers 1,2): W staged in LDS, in from global ----------
template<int K>
__global__ __launch_bounds__(256) void gates_part2(const float* __restrict__ W, long wS,
                                                   const float* __restrict__ in, int inS,
                                                   float* __restrict__ gp){
  __shared__ float wl[16][128];
  int tid = threadIdx.x;
  int rg = blockIdx.x % 288;
  int kc = blockIdx.x / 288;
  int r0 = rg*16;                       // [0, 4608)
  int s  = r0 / G3H;
  int g0 = r0 - s*G3H;
  int k0 = kc*128;
  const float* Wbase = W + (size_t)s*wS + (size_t)g0*K + k0;
  for (int q = tid; q < 16*32; q += 256){
    int r = q >> 5, i4 = q & 31;
    *(float4*)&wl[r][i4*4] = *(const float4*)(Wbase + (size_t)r*K + i4*4);
  }
  __syncthreads();
  int lane = tid & 63, wv = tid >> 6;
  int j = wv*4;
  const float4* w0 = (const float4*)wl[j];
  const float4* w1 = (const float4*)wl[j+1];
  const float4* w2 = (const float4*)wl[j+2];
  const float4* w3 = (const float4*)wl[j+3];
  const float* ip = in + (size_t)s*inS + (size_t)k0*64 + lane;
  float a0=0.f, a1=0.f, a2=0.f, a3=0.f;
  #pragma unroll 8
  for (int k4 = 0; k4 < 32; ++k4){
    float x0 = ip[(k4*4+0)*64];
    float x1 = ip[(k4*4+1)*64];
    float x2 = ip[(k4*4+2)*64];
    float x3 = ip[(k4*4+3)*64];
    float4 wa = w0[k4], wb = w1[k4], wc = w2[k4], wd = w3[k4];
    a0 += wa.x*x0 + wa.y*x1 + wa.z*x2 + wa.w*x3;
    a1 += wb.x*x0 + wb.y*x1 + wb.z*x2 + wb.w*x3;
    a2 += wc.x*x0 + wc.y*x1 + wc.z*x2 + wc.w*x3;
    a3 += wd.x*x0 + wd.y*x1 + wd.z*x2 + wd.w*x3;
  }
  float* op = gp + ((size_t)kc*4608 + r0 + j)*64 + lane;
  op[0] = a0; op[64] = a1; op[128] = a2; op[192] = a3;
}

// ---------- partial-reduce + GRU activation ----------
template<int NKC>
__global__ __launch_bounds__(256) void gru_act(const float* __restrict__ gp,
                                               const float* __restrict__ bih, long bihS,
                                               const float* __restrict__ bhh, long bhhS,
                                               float* __restrict__ h_all,
                                               float* __restrict__ hT_out, int writeHT, int l){
  int idx = blockIdx.x*256 + threadIdx.x;          // [0, 98304)
  int b = idx & 63;
  int h = (idx >> 6) & 511;
  int s = idx >> 15;
  size_t r = (size_t)s*G3H;
  float gr=0.f, gz=0.f, gn=0.f;
  #pragma unroll
  for (int kc = 0; kc < NKC; ++kc){
    const float* p = gp + (size_t)kc*294912;
    gr += p[(r + h)*64 + b];
    gz += p[(r + 512 + h)*64 + b];
    gn += p[(r + 1024 + h)*64 + b];
  }
  const float* bi = bih + (size_t)s*bihS;
  const float* bh = bhh + (size_t)s*bhhS;
  float rr = 1.f/(1.f + expf(-(gr + bi[h] + bh[h])));
  float zz = 1.f/(1.f + expf(-(gz + bi[512+h] + bh[512+h])));
  float nn = tanhf(gn + bi[1024+h] + rr*bh[1024+h]);
  float hv = (1.f - zz)*nn;
  h_all[(((size_t)s*BB + b)*3 + l)*HH + h] = hv;
  if (writeHT) hT_out[((size_t)s*HH + h)*BB + b] = hv;
}

// ---------- dots: one block per (s,b,l) row, 4-wave h-split ----------
__global__ __launch_bounds__(256) void dots2w(const float* __restrict__ h_all,
                                              const double* __restrict__ w_d,
                                              const float* __restrict__ Ws,
                                              double* __restrict__ score_d,
                                              double* __restrict__ dmat_d){
  __shared__ double red[4][4];
  int row = blockIdx.x;                            // [0, 576)
  int tid = threadIdx.x, lane = tid & 63, wv = tid >> 6;
  const float* hp = h_all + (size_t)row*HH;
  double a0=0.0, a1=0.0, a2=0.0, a3=0.0;
  #pragma unroll
  for (int jj = 0; jj < 2; ++jj){
    int h = wv*128 + jj*64 + lane;
    double hv = (double)hp[h];
    a0 += hv * w_d[h];
    a1 += hv * (double)Ws[h];
    a2 += hv * (double)Ws[768 + h];
    a3 += hv * (double)Ws[1536 + h];
  }
  for (int m = 32; m; m >>= 1){
    a0 += dshfl_xor(a0,m); a1 += dshfl_xor(a1,m);
    a2 += dshfl_xor(a2,m); a3 += dshfl_xor(a3,m);
  }
  if (lane == 0){ red[wv][0]=a0; red[wv][1]=a1; red[wv][2]=a2; red[wv][3]=a3; }
  __syncthreads();
  if (tid == 0){
    score_d[row]    = red[0][0]+red[1][0]+red[2][0]+red[3][0];
    dmat_d[row*3+0] = red[0][1]+red[1][1]+red[2][1]+red[3][1];
    dmat_d[row*3+1] = red[0][2]+red[1][2]+red[2][2]+red[3][2];
    dmat_d[row*3+2] = red[0][3]+red[1][3]+red[2][3]+red[3][3];
  }
}

// ---------- fused fold + xdot + softmax-sums: block t, 192 threads ----------
__global__ __launch_bounds__(192) void sums_x(const float* __restrict__ x,
                                              const float* __restrict__ Ws,
                                              const double* __restrict__ score_d,
                                              const double* __restrict__ dmat_d,
                                              const float* __restrict__ bs,
                                              int* __restrict__ Lint){
  __shared__ float xl[64*257];
  __shared__ float wsl[3*256];
  __shared__ double dl[3*64];
  __shared__ double P1L[576];
  int t = blockIdx.x, tid = threadIdx.x;
  int lane = tid & 63, w = tid >> 6;               // w = s (fold) / c (dot) / cur (final)
  for (int i = tid; i < 768; i += 192) wsl[i] = Ws[(i >> 8)*768 + 512 + (i & 255)];
  for (int q = tid; q < 4096; q += 192){           // stage x[:,t,:] via float4
    int r = q >> 6, i4 = q & 63;
    float4 v = *(const float4*)(x + ((size_t)r*TT + t)*IW + i4*4);
    float* dst = &xl[r*257 + i4*4];
    dst[0]=v.x; dst[1]=v.y; dst[2]=v.z; dst[3]=v.w;
  }
  {  // fold (redundant per block, cheap): P1L[s][c][b]
    int base = w*192 + lane*3;
    double s0 = score_d[base], s1 = score_d[base+1], s2 = score_d[base+2];
    double m = fmax(s0, fmax(s1, s2));
    double e0 = exp(s0-m), e1 = exp(s1-m), e2 = exp(s2-m);
    double inv = 1.0/(e0+e1+e2);
    e0 *= inv; e1 *= inv; e2 *= inv;
    for (int c = 0; c < 3; ++c){
      double v = e0*dmat_d[base*3 + c] + e1*dmat_d[(base+1)*3 + c] + e2*dmat_d[(base+2)*3 + c];
      P1L[(w*3 + c)*64 + lane] = v + (double)bs[c];
    }
  }
  __syncthreads();
  {
    const float* xr = &xl[lane*257];
    const float* wr = &wsl[w*256];
    double acc = 0.0;
    #pragma unroll 8
    for (int i = 0; i < 256; ++i) acc += (double)xr[i] * (double)wr[i];
    dl[w*64 + lane] = acc;
  }
  __syncthreads();
  double l0 = P1L[(w*3+0)*64 + lane] + dl[0*64 + lane];
  double l1 = P1L[(w*3+1)*64 + lane] + dl[1*64 + lane];
  double l2 = P1L[(w*3+2)*64 + lane] + dl[2*64 + lane];
  double m = fmax(l0, fmax(l1, l2));
  double e0 = exp(l0-m), e1 = exp(l1-m), e2 = exp(l2-m);
  double inv = 1.0/(e0+e1+e2);
  e0 *= inv; e1 *= inv; e2 *= inv;
  for (int mm = 32; mm; mm >>= 1){
    e0 += dshfl_xor(e0, mm); e1 += dshfl_xor(e1, mm); e2 += dshfl_xor(e2, mm);
  }
  if (lane == 0){
    int q0 = (int)lrintf(fmaxf(log2f((float)e0), -1500.f) * 1048576.0f);
    int q1 = (int)lrintf(fmaxf(log2f((float)e1), -1500.f) * 1048576.0f);
    int q2 = (int)lrintf(fmaxf(log2f((float)e2), -1500.f) * 1048576.0f);
    int* p = Lint + (size_t)t*12 + w*3;
    p[0] = (q0 & ~3) | 2;     // embed idx = 2-c so exact ties pick smallest c
    p[1] = (q1 & ~3) | 1;
    p[2] = (q2 & ~3) | 0;
  }
}

// ---------- VALU scan, 4-deep rotation: 12 outstanding ds_reads <= lgkmcnt max (15) ----------
// so the compiler can emit counted lgkmcnt waits instead of full drains.
#define LOADJ(S0,S1,S2x, tt) do { int _t = (tt); if (_t > 511) _t = 511;   \
  const int4* _p = (const int4*)&lds[_t*12]; S0=_p[0]; S1=_p[1];           \
  S2x = lds[_t*12 + 8]; } while(0)

#define STEPJ(S0,S1,S2x, kk) do {                               \
  int L0 = (idx==2)?S0.x:((idx==1)?S0.w:S1.z);                  \
  int L1 = (idx==2)?S0.y:((idx==1)?S1.x:S1.w);                  \
  int L2 = (idx==2)?S0.z:((idx==1)?S1.y:S2x);                   \
  int v0 = L0-a0, v1 = L1-a1, v2 = L2-a2;                       \
  int bm = v0 > v1 ? v0 : v1; bm = bm > v2 ? bm : v2;           \
  idx = bm & 3;                                                 \
  a0 += (idx==2) ? PEN1 : 0;                                    \
  a1 += (idx==1) ? PEN1 : 0;                                    \
  a2 += (idx==0) ? PEN1 : 0;                                    \
  word |= (unsigned)(2 - idx) << (2*(kk)); } while(0)

__global__ __launch_bounds__(64) void scan8(const int* __restrict__ Lint,
                                            unsigned* __restrict__ curpack){
  __shared__ int lds[TT*12];
  int lane = threadIdx.x;
  for (int i = lane*4; i < TT*12; i += 256)
    *(int4*)&lds[i] = *(const int4*)&Lint[i];
  __syncthreads();
  int a0 = PEN1, a1 = 0, a2 = 0, idx = 2;          // pen exps [1,0,0]; cur=0 -> idx=2
  // buffer by (t & 3): 0->P, 1->Q, 2->R, 3->S
  int4 P0,P1, Q0,Q1, R0,R1, S0,S1;
  int  P2, Q2, R2, S2;
  LOADJ(Q0,Q1,Q2, 1); LOADJ(R0,R1,R2, 2); LOADJ(S0,S1,S2, 3); LOADJ(P0,P1,P2, 4);
  {  // group 0: steps 1..15 (t=0 fixed cur=0, bits stay 0)
    unsigned word = 0u;
    STEPJ(Q0,Q1,Q2, 1);   LOADJ(Q0,Q1,Q2, 5);
    STEPJ(R0,R1,R2, 2);   LOADJ(R0,R1,R2, 6);
    STEPJ(S0,S1,S2, 3);   LOADJ(S0,S1,S2, 7);
    STEPJ(P0,P1,P2, 4);   LOADJ(P0,P1,P2, 8);
    STEPJ(Q0,Q1,Q2, 5);   LOADJ(Q0,Q1,Q2, 9);
    STEPJ(R0,R1,R2, 6);   LOADJ(R0,R1,R2, 10);
    STEPJ(S0,S1,S2, 7);   LOADJ(S0,S1,S2, 11);
    STEPJ(P0,P1,P2, 8);   LOADJ(P0,P1,P2, 12);
    STEPJ(Q0,Q1,Q2, 9);   LOADJ(Q0,Q1,Q2, 13);
    STEPJ(R0,R1,R2, 10);  LOADJ(R0,R1,R2, 14);
    STEPJ(S0,S1,S2, 11);  LOADJ(S0,S1,S2, 15);
    STEPJ(P0,P1,P2, 12);  LOADJ(P0,P1,P2, 16);
    STEPJ(Q0,Q1,Q2, 13);  LOADJ(Q0,Q1,Q2, 17);
    STEPJ(R0,R1,R2, 14);  LOADJ(R0,R1,R2, 18);
    STEPJ(S0,S1,S2, 15);  LOADJ(S0,S1,S2, 19);
    if (lane == 0) curpack[0] = word;
  }
  for (int base = 16; base < 512; base += 16){
    unsigned word = 0u;
    STEPJ(P0,P1,P2, 0);   LOADJ(P0,P1,P2, base+4);
    STEPJ(Q0,Q1,Q2, 1);   LOADJ(Q0,Q1,Q2, base+5);
    STEPJ(R0,R1,R2, 2);   LOADJ(R0,R1,R2, base+6);
    STEPJ(S0,S1,S2, 3);   LOADJ(S0,S1,S2, base+7);
    STEPJ(P0,P1,P2, 4);   LOADJ(P0,P1,P2, base+8);
    STEPJ(Q0,Q1,Q2, 5);   LOADJ(Q0,Q1,Q2, base+9);
    STEPJ(R0,R1,R2, 6);   LOADJ(R0,R1,R2, base+10);
    STEPJ(S0,S1,S2, 7);   LOADJ(S0,S1,S2, base+11);
    STEPJ(P0,P1,P2, 8);   LOADJ(P0,P1,P2, base+12);
    STEPJ(Q0,Q1,Q2, 9);   LOADJ(Q0,Q1,Q2, base+13);
    STEPJ(R0,R1,R2, 10);  LOADJ(R0,R1,R2, base+14);
    STEPJ(S0,S1,S2, 11);  LOADJ(S0,S1,S2, base+15);
    STEPJ(P0,P1,P2, 12);  LOADJ(P0,P1,P2, base+16);
    STEPJ(Q0,Q1,Q2, 13);  LOADJ(Q0,Q1,Q2, base+17);
    STEPJ(R0,R1,R2, 14);  LOADJ(R0,R1,R2, base+18);
    STEPJ(S0,S1,S2, 15);  LOADJ(S0,S1,S2, base+19);
    if (lane == 0) curpack[base >> 4] = word;
  }
}

// ---------- outputs (f32), fused; cur from 2-bit packed words ----------
__global__ __launch_bounds__(256) void out_all(const float* __restrict__ h_all,
                                               const unsigned* __restrict__ curpack,
                                               float* __restrict__ out){
  int blk = blockIdx.x;
  if (blk < 512){
    int t = blk;
    int cur = (int)((curpack[t >> 4] >> ((t & 15)*2)) & 3u);
    const float* base = h_all + (size_t)cur*98304 + 2*HH;  // [cur][b][2][:], b-stride 1536
    int tid = threadIdx.x;
    for (int k = 0; k < 32; ++k){
      int e4 = (k*256 + tid)*4;                            // [0, 32768)
      int b = e4 >> 9, h = e4 & 511;
      float4 v = *(const float4*)(base + (size_t)b*1536 + h);
      *(float4*)(&out[((size_t)b*TT + t)*HH + h]) = v;
    }
  } else {
    int cur = (int)((curpack[31] >> 30) & 3u);
    int e4 = ((blk - 512)*256 + threadIdx.x)*4;            // [0, 98304)
    float4 v = *(const float4*)(h_all + (size_t)cur*98304 + e4);
    *(float4*)(&out[(size_t)BB*TT*HH + e4]) = v;
  }
}

extern "C" void kernel_launch(void* const* d_in, const int* in_sizes, int n_in,
                              void* d_out, int out_size, void* d_ws, size_t ws_size,
                              hipStream_t stream){
  const float* x    = (const float*)d_in[0];
  const float* Wl   = (const float*)d_in[1];
  // d_in[2] = bl : constant over L inside softmax -> cancels; unused
  const float* Ws   = (const float*)d_in[3];
  const float* bs   = (const float*)d_in[4];
  const float* Wih0 = (const float*)d_in[5];
  const float* bih0 = (const float*)d_in[6];
  const float* bhh0 = (const float*)d_in[7];
  const float* WihL = (const float*)d_in[8];
  const float* bihL = (const float*)d_in[9];
  const float* bhhL = (const float*)d_in[10];
  float* out = (float*)d_out;

  // ---- sentinels ----
  static const int exp_sizes[11] = {8388608, 262144, 512, 2304, 3,
                                    1179648, 4608, 4608, 4718592, 9216, 9216};
  int bad = 0;
  if (n_in != 11) bad = 13;
  else {
    for (int i = 0; i < 11; ++i) if (in_sizes[i] != exp_sizes[i]) { bad = i + 1; break; }
  }
  if (!bad && out_size != 16875520) bad = 12;
  if (bad){
    sentinel_k<<<dim3(1), dim3(1), 0, stream>>>(out, 1048576.0f * (float)bad);
    return;
  }
  if (ws_size < 1292416){
    sentinel_k<<<dim3(1), dim3(1), 0, stream>>>(out, 3.0e7f + (float)(ws_size >> 6));
    return;
  }

  // ---- ws layout ----
  double*   w_d     = (double*)d_ws;              // 512 f64
  double*   score_d = w_d + 512;                  // 576 f64
  double*   dmat_d  = score_d + 576;              // 1728 f64
  int*      Lint    = (int*)(dmat_d + 1728);      // 6144 i32
  float*    h_all   = (float*)(Lint + 6144);      // 294912 f32
  float*    x0T     = h_all + 294912;             // 16384 f32 (unused hole, kept for layout stability)
  unsigned* curpack = (unsigned*)(x0T + 16384);   // 32 u32

  // ---- big scratch in d_out tail (dead before out_all writes) ----
  char* outb = (char*)d_out;
  float* gip = (float*)(outb + 50331648);         // [4][4608][64] f32 = 4,718,592 B
  float* hT0 = gip + 1179648;                     // [3][512][64]  f32 =   393,216 B
  float* hT1 = hT0 + 98304;                       // same

  // GRU stack: K-split partial GEMM (LDS W) + activation
  gates0x         <<<dim3(584),  dim3(256), 0, stream>>>(x, Wih0, Wl, w_d, gip);
  gru_act<2>      <<<dim3(384),  dim3(256), 0, stream>>>(gip, bih0, G3H, bhh0, G3H, h_all, hT0, 1, 0);
  gates_part2<512><<<dim3(1152), dim3(256), 0, stream>>>(WihL, (long)2*G3H*HH, hT0, HH*BB, gip);
  gru_act<4>      <<<dim3(384),  dim3(256), 0, stream>>>(gip, bihL, 2*G3H, bhhL, 2*G3H, h_all, hT1, 1, 1);
  gates_part2<512><<<dim3(1152), dim3(256), 0, stream>>>(WihL + (size_t)G3H*HH, (long)2*G3H*HH, hT1, HH*BB, gip);
  gru_act<4>      <<<dim3(384),  dim3(256), 0, stream>>>(gip, bihL + G3H, 2*G3H, bhhL + G3H, 2*G3H, h_all, hT0, 0, 2);

  dots2w<<<dim3(576), dim3(256), 0, stream>>>(h_all, w_d, Ws, score_d, dmat_d);
  sums_x<<<dim3(512), dim3(192), 0, stream>>>(x, Ws, score_d, dmat_d, bs, Lint);

  scan8<<<dim3(1), dim3(64), 0, stream>>>(Lint, curpack);

  out_all<<<dim3(608), dim3(256), 0, stream>>>(h_all, curpack, out);
}